// Round 11
// baseline (2035.494 us; speedup 1.0000x reference)
//
#include <hip/hip_runtime.h>
#include <math.h>

// ---------------------------------------------------------------------------
// FullModelPCN: FPS + Sinkhorn-EMD (x2) + Chamfer (x2) + passthrough
// B=4; N1=1024 (coarse), N2=4096 (fine/gt).
//
// Round-23 structure (base: round-22, 1086 us):
//   fps: DUAL-BATCH blocks (2 blocks, each runs 2 batches interleaved).
//   Per step: leafA+publishA -> leafB+publishB -> pollA+selectA ->
//   pollB+selectB. Batch A's LDS exchange visibility hides under batch B's
//   compute and vice versa; the f.sq[winner] read overlaps the other batch's
//   poll. Packed f32x2 register arrays (64 VGPR/batch) avoid r4's spill.
//   All tournament comparisons lexicographic (max val, min idx) -> selection
//   bit-identical. LDS: 2x64KB point sets = 131.7KB (static, 1 block/CU).
//   emd2/emd1/chamfer identical to round-22 (absmax 0 proven).
// ---------------------------------------------------------------------------

#define LOG2E 1.4426950408889634f
#define LN2   0.6931471805599453f
#define NEGBIG -3.0e38f

// sync region (uints, 4096, memset 0 per call):
//   emd2 slots:  b*512 + j*16           -> [0, 2048)
//   fps-done:    2048 + b*16            -> [2048, 2112)
//   emd1-done:   2112 + b*16            -> [2112, 2176)
#define SY2(b) ((b) * 512)
#define SYF(b) (2048 + (b) * 16)
#define SYD(b) (2112 + (b) * 16)

typedef float f32x2 __attribute__((ext_vector_type(2)));

#if __has_builtin(__builtin_amdgcn_exp2f)
__device__ __forceinline__ float fexp2(float x) { return __builtin_amdgcn_exp2f(x); }
#else
__device__ __forceinline__ float fexp2(float x) { return exp2f(x); }
#endif

__device__ __forceinline__ float dist_rn(float x, float y, float z,
                                         float qx, float qy, float qz) {
  float dx = __fsub_rn(x, qx), dy = __fsub_rn(y, qy), dz = __fsub_rn(z, qz);
  return __fadd_rn(__fadd_rn(__fmul_rn(dx, dx), __fmul_rn(dy, dy)),
                   __fmul_rn(dz, dz));
}

// packed pair distance: per-element IEEE RN sub/mul/add in the exact
// ((xx+yy)+zz) order with contraction OFF -> bit-identical to dist_rn.
__device__ __forceinline__ f32x2 dist2_rn(f32x2 x, f32x2 y, f32x2 z,
                                          float qx, float qy, float qz) {
#pragma clang fp contract(off)
  f32x2 dx = x - qx;
  f32x2 dy = y - qy;
  f32x2 dz = z - qz;
  f32x2 xx = dx * dx;
  f32x2 yy = dy * dy;
  f32x2 zz = dz * dz;
  return (xx + yy) + zz;
}

// ------------------------------ shared memory -------------------------------
struct FpsP {
  float4 sq[4096];
  unsigned long long xch[4][2];  // [wave][step parity] tagged winner
  int sIdx[64];                  // ring of winning indices (steps s&63)
};
struct FpsS {
  FpsP p[2];  // two batches per fps block
};
struct WorkS {
  float4 ldsRow[256];
  float4 ldsC[1024];
  float ldsG2[1024];
  float red[8];
};
struct Emd1S {
  float4 rowsO[1024];     // o1 points; .w = f-weight (odd-round rows)
  float4 rowsG[1024];     // gt_fps points; .w = g-weight (even-round rows)
  float2 part[2][16][64]; // [round parity][chunk][col-lane] partials
  float g2[1024];         // assign1 fold: w + |q|^2
  float red[8];
};
union SmemAll {
  FpsS f;   // ~131.7 KB -> 1 block/CU everywhere
  WorkS w;
  Emd1S e;
};

// ------------------------------ args ----------------------------------------
struct UniArgs {
  const float* gt;
  const float* epsP;
  const float4 *o1P4, *o2P4, *gtP4;
  float4* gfP4;
  float2 *gpart2, *fpart2, *apart2;
  unsigned long long* vecT;  // [0,4096): g tagged; [4096,8192): f tagged
  unsigned* sync;
  float* out;
  int NC2, BPB;
};

// ------------------- distributed-arrival relaxed barriers -------------------
__device__ __forceinline__ void bar_signal(unsigned* slot, unsigned val) {
  __syncthreads();
  if (threadIdx.x == 0)
    __hip_atomic_store(slot, val, __ATOMIC_RELEASE, __HIP_MEMORY_SCOPE_AGENT);
}
template <int SLP>
__device__ __forceinline__ void bar_waitall(const unsigned* base, int n,
                                            unsigned target) {
  if (threadIdx.x < 64) {
    int l = threadIdx.x;
    for (;;) {
      unsigned v = (l < n)
                       ? __hip_atomic_load(base + l * 16, __ATOMIC_RELAXED,
                                           __HIP_MEMORY_SCOPE_AGENT)
                       : target;
      if (__all((int)(v >= target))) break;
      __builtin_amdgcn_s_sleep(SLP);
    }
    if (l == 0)
      (void)__hip_atomic_load(base, __ATOMIC_ACQUIRE, __HIP_MEMORY_SCOPE_AGENT);
  }
  __syncthreads();
}

__device__ __forceinline__ float blockRedSum(float v, float* red4) {
#pragma unroll
  for (int m = 32; m; m >>= 1) v += __shfl_xor(v, m, 64);
  int lane = threadIdx.x & 63, wid = threadIdx.x >> 6;
  __syncthreads();
  if (lane == 0) red4[wid] = v;
  __syncthreads();
  float s = 0.0f;
  if (threadIdx.x == 0) {
#pragma unroll
    for (int w = 0; w < 4; ++w) s += red4[w];
  }
  return s;
}

// ---- branchless 4-wide tagged poll (thread-strided slots) ------------------
__device__ __forceinline__ void poll4(const unsigned long long* v, int tid,
                                      unsigned want, float* w0, float* w1,
                                      float* w2, float* w3) {
  unsigned long long p0, p1, p2, p3;
  for (;;) {
    p0 = __hip_atomic_load(v + tid, __ATOMIC_RELAXED, __HIP_MEMORY_SCOPE_AGENT);
    p1 = __hip_atomic_load(v + tid + 256, __ATOMIC_RELAXED, __HIP_MEMORY_SCOPE_AGENT);
    p2 = __hip_atomic_load(v + tid + 512, __ATOMIC_RELAXED, __HIP_MEMORY_SCOPE_AGENT);
    p3 = __hip_atomic_load(v + tid + 768, __ATOMIC_RELAXED, __HIP_MEMORY_SCOPE_AGENT);
    if ((unsigned)(p0 >> 32) >= want && (unsigned)(p1 >> 32) >= want &&
        (unsigned)(p2 >> 32) >= want && (unsigned)(p3 >> 32) >= want)
      break;
    __builtin_amdgcn_s_sleep(1);
  }
  *w0 = __uint_as_float((unsigned)p0);
  *w1 = __uint_as_float((unsigned)p1);
  *w2 = __uint_as_float((unsigned)p2);
  *w3 = __uint_as_float((unsigned)p3);
}

// ---- moderate FMA burst (r6 duty: ~256 FMAs/poll) --------------------------
__device__ __forceinline__ void fma_burst(float* a) {
#pragma unroll
  for (int i = 0; i < 64; ++i) {
    a[0] = fmaf(a[0], 1.0000001f, 1.0e-6f);
    a[1] = fmaf(a[1], 1.0000001f, 1.0e-6f);
    a[2] = fmaf(a[2], 1.0000001f, 1.0e-6f);
    a[3] = fmaf(a[3], 1.0000001f, 1.0e-6f);
  }
}

// ---- warm spin: FMA until all 4 emd1-done flags set ------------------------
__device__ void warm_spin(const UniArgs& A) {
  float a[4] = {(float)(threadIdx.x + 1), 1.5f, 2.5f, 3.5f};
  const unsigned* sy = A.sync;
  for (;;) {
    unsigned d0 = __hip_atomic_load(sy + SYD(0), __ATOMIC_RELAXED, __HIP_MEMORY_SCOPE_AGENT);
    unsigned d1 = __hip_atomic_load(sy + SYD(1), __ATOMIC_RELAXED, __HIP_MEMORY_SCOPE_AGENT);
    unsigned d2 = __hip_atomic_load(sy + SYD(2), __ATOMIC_RELAXED, __HIP_MEMORY_SCOPE_AGENT);
    unsigned d3 = __hip_atomic_load(sy + SYD(3), __ATOMIC_RELAXED, __HIP_MEMORY_SCOPE_AGENT);
    if ((d0 & d1 & d2 & d3) != 0u) break;
    fma_burst(a);
  }
  asm volatile("" ::"v"(a[0]), "v"(a[1]), "v"(a[2]), "v"(a[3]));
}

// ---- warm wait on one flag (FMA-dense), with acquire + block barrier -------
__device__ void warm_wait1(const unsigned* slot, unsigned target) {
  float a[4] = {(float)(threadIdx.x + 1), 1.5f, 2.5f, 3.5f};
  for (;;) {
    unsigned v = __hip_atomic_load(slot, __ATOMIC_RELAXED, __HIP_MEMORY_SCOPE_AGENT);
    if (v >= target) break;
    fma_burst(a);
  }
  asm volatile("" ::"v"(a[0]), "v"(a[1]), "v"(a[2]), "v"(a[3]));
  if (threadIdx.x == 0)
    (void)__hip_atomic_load(slot, __ATOMIC_ACQUIRE, __HIP_MEMORY_SCOPE_AGENT);
  __syncthreads();
}

// --------------------------- prep: build P4 arrays --------------------------
__global__ __launch_bounds__(256) void prep_kernel(
    const float* __restrict__ o1, const float* __restrict__ o2,
    const float* __restrict__ gt, const float* __restrict__ epsP,
    float4* __restrict__ o1P4, float4* __restrict__ o2P4,
    float4* __restrict__ gtP4) {
  int id = blockIdx.x * 256 + threadIdx.x;  // 0..36863
  float eps = *epsP;
  float se = (1.0f / eps) * LOG2E;
  float kxy = sqrtf(se + se);
  const float* src;
  float4* dst;
  if (id < 4096) { src = o1 + 3 * id; dst = o1P4 + id; }
  else if (id < 20480) { int p = id - 4096; src = o2 + 3 * p; dst = o2P4 + p; }
  else { int p = id - 20480; src = gt + 3 * p; dst = gtP4 + p; }
  float x = src[0], y = src[1], z = src[2];
  float xx = x * x + y * y + z * z;
  *dst = make_float4(kxy * x, kxy * y, kxy * z, xx * se);
}

// --------------------------- Sinkhorn LSE helpers ---------------------------
template <int NC>
__device__ __forceinline__ float finalize_w(const float2* __restrict__ part,
                                            int gi, int stride, float nloga2) {
  float2 pp[NC];
#pragma unroll
  for (int c = 0; c < NC; ++c) pp[c] = part[c * stride + gi];
  float m = pp[0].x;
#pragma unroll
  for (int c = 1; c < NC; ++c) m = fmaxf(m, pp[c].x);
  float s = 0.0f;
#pragma unroll
  for (int c = 0; c < NC; ++c) s += pp[c].y * fexp2(pp[c].x - m);
  return nloga2 - (m + __log2f(s));
}

// emd2 pass: block = (b, cb in 0..1, ch in 0..NC-1); 2048 cols (8/thread)
template <int NC>
__device__ void pass2_job(int b, int cb, int ch, const float4* __restrict__ rowP,
                          const float4* __restrict__ colP,
                          const float2* __restrict__ vpart,
                          float2* __restrict__ dst, float4* ldsRow) {
  const int CH = 4096 / NC;
  int tid = threadIdx.x;
  int gj = b * 4096 + cb * 2048 + tid;
  float cx[8], cy[8], cz[8];
#pragma unroll
  for (int c = 0; c < 8; ++c) {
    float4 cp = colP[gj + (c << 8)];
    cx[c] = cp.x; cy[c] = cp.y; cz[c] = cp.z;
  }
  float M[8], S[8];
#pragma unroll
  for (int c = 0; c < 8; ++c) { M[c] = NEGBIG; S[c] = 0.0f; }
  int r0 = ch * CH;
  for (int t0 = 0; t0 < CH; t0 += 256) {
    __syncthreads();
    {
      int gi = b * 4096 + r0 + t0 + tid;
      float4 rp = rowP[gi];
      float w = vpart ? finalize_w<NC>(vpart, gi, 16384, 12.0f) : -rp.w;
      ldsRow[tid] = make_float4(rp.x, rp.y, rp.z, w);
    }
    __syncthreads();
#pragma unroll 1
    for (int r = 0; r < 256; r += 8) {
      float4 q[8];
#pragma unroll
      for (int u = 0; u < 8; ++u) q[u] = ldsRow[r + u];
#pragma unroll
      for (int c = 0; c < 8; ++c) {
        float t[8];
#pragma unroll
        for (int u = 0; u < 8; ++u)
          t[u] = fmaf(cx[c], q[u].x, fmaf(cy[c], q[u].y, fmaf(cz[c], q[u].z, q[u].w)));
        float cm = fmaxf(fmaxf(fmaxf(t[0], t[1]), fmaxf(t[2], t[3])),
                         fmaxf(fmaxf(t[4], t[5]), fmaxf(t[6], t[7])));
        float nM = fmaxf(M[c], cm);
        float s8 = ((fexp2(t[0] - nM) + fexp2(t[1] - nM)) +
                    (fexp2(t[2] - nM) + fexp2(t[3] - nM))) +
                   ((fexp2(t[4] - nM) + fexp2(t[5] - nM)) +
                    (fexp2(t[6] - nM) + fexp2(t[7] - nM)));
        S[c] = fmaf(S[c], fexp2(M[c] - nM), s8);
        M[c] = nM;
      }
    }
  }
#pragma unroll
  for (int c = 0; c < 8; ++c)
    dst[ch * 16384 + gj + (c << 8)] = make_float2(M[c], S[c]);
}

// ------------------------------- chamfer ------------------------------------
__device__ void cham_job(const float4* __restrict__ aP, const float4* __restrict__ bP,
                         int Na, int Nb, float* outP, float* outT,
                         float scaleP, float scaleT, int b, int rb,
                         WorkS& w, const float* epsP) {
  int tid = threadIdx.x;
  int i0 = rb * 512 + tid, i1 = i0 + 256;
  float4 a0 = aP[b * Na + i0], a1 = aP[b * Na + i1];
  float m0 = 3.0e38f, m1 = 3.0e38f;
  for (int t0 = 0; t0 < Nb; t0 += 1024) {
    __syncthreads();
    for (int t = tid; t < 1024; t += 256) w.ldsC[t] = bP[b * Nb + t0 + t];
    __syncthreads();
#pragma unroll 4
    for (int t = 0; t < 1024; ++t) {
      float4 q = w.ldsC[t];
      float c0 = fmaf(-a0.z, q.z, fmaf(-a0.y, q.y, fmaf(-a0.x, q.x, q.w + a0.w)));
      float c1 = fmaf(-a1.z, q.z, fmaf(-a1.y, q.y, fmaf(-a1.x, q.x, q.w + a1.w)));
      m0 = fminf(m0, c0);
      m1 = fminf(m1, c1);
    }
  }
  float eps = *epsP;
  float inv_se = eps * LN2;
  float d0 = fmaxf(0.0f, m0 * inv_se), d1 = fmaxf(0.0f, m1 * inv_se);
  float s1 = blockRedSum(sqrtf(d0) + sqrtf(d1), w.red);
  float s2 = blockRedSum(d0 + d1, w.red);
  if (tid == 0) {
    atomicAdd(outP, s1 * scaleP);
    atomicAdd(outT, s2 * scaleT);
  }
}

__device__ void chamfer_worker(int g, const UniArgs& A, WorkS& w) {
  for (int cj = g; cj < 104; cj += 88) {
    if (cj < 32) {
      cham_job(A.gtP4, A.o2P4, 4096, 4096, A.out + 61452 + (cj >> 3),
               A.out + 61460 + (cj >> 3), 1.0f / 8192.0f, 1.0f / 4096.0f,
               cj >> 3, cj & 7, w, A.epsP);
    } else if (cj < 64) {
      int j = cj - 32;
      cham_job(A.o2P4, A.gtP4, 4096, 4096, A.out + 61452 + (j >> 3),
               A.out + 61460 + (j >> 3), 1.0f / 8192.0f, 1.0f / 4096.0f,
               j >> 3, j & 7, w, A.epsP);
    } else if (cj < 96) {
      int j = cj - 64;
      cham_job(A.gtP4, A.o1P4, 4096, 1024, A.out + 61448 + (j >> 3),
               A.out + 61456 + (j >> 3), 1.0f / 8192.0f, 1.0f / 4096.0f,
               j >> 3, j & 7, w, A.epsP);
    } else {
      int j = cj - 96;
      cham_job(A.o1P4, A.gtP4, 1024, 4096, A.out + 61448 + (j >> 1),
               A.out + 61456 + (j >> 1), 1.0f / 2048.0f, 1.0f / 1024.0f,
               j >> 1, j & 1, w, A.epsP);
    }
  }
}

// ------------------------------- assign2 ------------------------------------
template <int NC>
__device__ void assign2_job(int b, int cc, int rb, const UniArgs& A, WorkS& w) {
  int tid = threadIdx.x;
  __syncthreads();
  for (int t = tid; t < 1024; t += 256) {
    int gjc = b * 4096 + cc * 1024 + t;
    float wv = finalize_w<NC>(A.gpart2, gjc, 16384, 12.0f);
    float4 qp = A.gtP4[gjc];
    w.ldsC[t] = make_float4(qp.x, qp.y, qp.z, wv);
    w.ldsG2[t] = wv + qp.w;
  }
  __syncthreads();
#pragma unroll
  for (int rr = 0; rr < 2; ++rr) {
    int gi = b * 4096 + rb * 512 + (rr << 8) + tid;
    float4 rp = A.o2P4[gi];
    float rx = rp.x, ry = rp.y, rz = rp.z, xw = rp.w;
    float bW = NEGBIG;
    int bj = 0;
    for (int t = 0; t < 1024; ++t) {
      float4 q = w.ldsC[t];
      float W = fmaf(rz, q.z, fmaf(ry, q.y, fmaf(rx, q.x, q.w - xw)));
      W = fminf(W, w.ldsG2[t]);
      if (W > bW) { bW = W; bj = cc * 1024 + t; }
    }
    A.apart2[cc * 16384 + gi] = make_float2(bW, __int_as_float(bj));
  }
}

__device__ void combine2_job(int b, int rb, const UniArgs& A, WorkS& w) {
  int tid = threadIdx.x;
  int gi = b * 4096 + (rb << 8) + tid;
  float bW = NEGBIG;
  int bj = 0;
#pragma unroll
  for (int c = 0; c < 4; ++c) {
    float2 p = A.apart2[c * 16384 + gi];
    if (p.x > bW) { bW = p.x; bj = __float_as_int(p.y); }
  }
  float eps = *A.epsP;
  float inv_se = eps * LN2;
  float4 rp = A.o2P4[gi];
  float4 qp = A.gtP4[b * 4096 + bj];
  float dotp = rp.x * qp.x + rp.y * qp.y + rp.z * qp.z;
  float d = fmaxf(0.0f, (rp.w + qp.w - dotp) * inv_se);
  float s = blockRedSum(sqrtf(d), w.red);
  if (tid == 0) atomicAdd(A.out + 61444 + b, s * (1.0f / 4096.0f));
}

// --------------------------- FPS building blocks ----------------------------
// leaf + wave tournament + DPP reduce + cross-lane tree -> (wv, wi).
// All comparisons lexicographic (max value, min index) -> order-independent.
__device__ __forceinline__ void leaf_reduce(f32x2* PX, f32x2* PY, f32x2* PZ,
                                            f32x2* D, float qx, float qy,
                                            float qz, int tid, unsigned& wvO,
                                            int& wiO) {
  float tv[8]; int ti[8];
#pragma unroll
  for (int i = 0; i < 8; ++i) {
    f32x2 nn = dist2_rn(PX[i], PY[i], PZ[i], qx, qy, qz);
    float n0 = fminf(D[i][0], nn[0]);
    float n1 = fminf(D[i][1], nn[1]);
    D[i][0] = n0;
    D[i][1] = n1;
    bool t = n1 > n0;
    tv[i] = t ? n1 : n0;
    ti[i] = tid + ((t ? (2 * i + 1) : (2 * i)) << 8);
  }
  float uv[4]; int ui[4];
#pragma unroll
  for (int i = 0; i < 4; ++i) {
    bool t = tv[2 * i + 1] > tv[2 * i];
    uv[i] = t ? tv[2 * i + 1] : tv[2 * i];
    ui[i] = t ? ti[2 * i + 1] : ti[2 * i];
  }
  bool tA = uv[1] > uv[0];
  float vA = tA ? uv[1] : uv[0]; int iA = tA ? ui[1] : ui[0];
  bool tB = uv[3] > uv[2];
  float vB = tB ? uv[3] : uv[2]; int iB = tB ? ui[3] : ui[2];
  bool tC = vB > vA;
  float bv = tC ? vB : vA; int bi = tC ? iB : iA;
  unsigned bvu = __float_as_uint(bv);
#define DPPSTEP(C)                                                             \
  {                                                                            \
    unsigned ov = (unsigned)__builtin_amdgcn_update_dpp(0, (int)bvu, C, 0xf,  \
                                                        0xf, true);           \
    int oi = __builtin_amdgcn_update_dpp(0, bi, C, 0xf, 0xf, true);           \
    bool t = (ov > bvu) || ((ov == bvu) && ((unsigned)oi < (unsigned)bi));    \
    bvu = t ? ov : bvu;                                                        \
    bi = t ? oi : bi;                                                          \
  }
  DPPSTEP(0xB1)
  DPPSTEP(0x4E)
  DPPSTEP(0x141)
  DPPSTEP(0x140)
#undef DPPSTEP
  unsigned r0v = (unsigned)__builtin_amdgcn_readlane((int)bvu, 0);
  int r0i = __builtin_amdgcn_readlane(bi, 0);
  unsigned r1v = (unsigned)__builtin_amdgcn_readlane((int)bvu, 16);
  int r1i = __builtin_amdgcn_readlane(bi, 16);
  unsigned r2v = (unsigned)__builtin_amdgcn_readlane((int)bvu, 32);
  int r2i = __builtin_amdgcn_readlane(bi, 32);
  unsigned r3v = (unsigned)__builtin_amdgcn_readlane((int)bvu, 48);
  int r3i = __builtin_amdgcn_readlane(bi, 48);
  bool tP = (r1v > r0v) || (r1v == r0v && r1i < r0i);
  unsigned pv = tP ? r1v : r0v; int pi = tP ? r1i : r0i;
  bool tQ = (r3v > r2v) || (r3v == r2v && r3i < r2i);
  unsigned qv = tQ ? r3v : r2v; int qi = tQ ? r3i : r2i;
  bool tR = (qv > pv) || (qv == pv && qi < pi);
  wvO = tR ? qv : pv;
  wiO = tR ? qi : pi;
}

__device__ __forceinline__ int poll_sel(unsigned long long (*xch)[2], int w,
                                        int par, unsigned tagw, unsigned wv,
                                        int wi) {
  unsigned long long g1, g2, g3;
  for (;;) {
    g1 = __hip_atomic_load(&xch[(w + 1) & 3][par], __ATOMIC_RELAXED,
                           __HIP_MEMORY_SCOPE_WORKGROUP);
    g2 = __hip_atomic_load(&xch[(w + 2) & 3][par], __ATOMIC_RELAXED,
                           __HIP_MEMORY_SCOPE_WORKGROUP);
    g3 = __hip_atomic_load(&xch[(w + 3) & 3][par], __ATOMIC_RELAXED,
                           __HIP_MEMORY_SCOPE_WORKGROUP);
    if ((((unsigned)(g1 >> 16) & 1023u) == tagw) &
        (((unsigned)(g2 >> 16) & 1023u) == tagw) &
        (((unsigned)(g3 >> 16) & 1023u) == tagw))
      break;
  }
  unsigned bv2 = wv; int bi2 = wi;
#define XCOMB(G)                                                               \
  {                                                                            \
    unsigned _v = (unsigned)((G) >> 32);                                       \
    int _i = (int)((unsigned)(G) & 0xFFFu);                                    \
    if (_v > bv2 || (_v == bv2 && _i < bi2)) { bv2 = _v; bi2 = _i; }          \
  }
  XCOMB(g1) XCOMB(g2) XCOMB(g3)
#undef XCOMB
  return bi2;
}

// --------------------------------- FPS --------------------------------------
// Dual-batch fps block: batches (b0, b0+1); interleaved steps hide each
// batch's LDS exchange latency under the other's compute. Selection
// bit-identical (lexicographic tournaments, packed RN arithmetic).
__device__ void fps_role2(const UniArgs& A, int b0, FpsS& f) {
  int tid = threadIdx.x;
#pragma unroll
  for (int h = 0; h < 2; ++h) {
    const float* base = A.gt + (b0 + h) * 12288;
    for (int t = tid; t < 4096; t += 256) {
      float x = base[3 * t], y = base[3 * t + 1], z = base[3 * t + 2];
      f.p[h].sq[t] = make_float4(x, y, z, x * x + y * y + z * z);
    }
  }
  if (tid < 8) {
    ((unsigned long long*)f.p[0].xch)[tid] = 0ull;
    ((unsigned long long*)f.p[1].xch)[tid] = 0ull;
  }
  if (tid == 0) { f.p[0].sIdx[0] = 0; f.p[1].sIdx[0] = 0; }
  __syncthreads();
  float eps = *A.epsP;
  float se = (1.0f / eps) * LOG2E;
  float kxy = sqrtf(se + se);
  int lane = tid & 63, w = tid >> 6;

  float4 p0A = f.p[0].sq[0];
  float4 p0B = f.p[1].sq[0];
  f32x2 PXA[8], PYA[8], PZA[8], DA[8];
  f32x2 PXB[8], PYB[8], PZB[8], DB[8];
#pragma unroll
  for (int k = 0; k < 16; ++k) {
    float4 pa = f.p[0].sq[tid + (k << 8)];
    PXA[k >> 1][k & 1] = pa.x;
    PYA[k >> 1][k & 1] = pa.y;
    PZA[k >> 1][k & 1] = pa.z;
    float4 pb = f.p[1].sq[tid + (k << 8)];
    PXB[k >> 1][k & 1] = pb.x;
    PYB[k >> 1][k & 1] = pb.y;
    PZB[k >> 1][k & 1] = pb.z;
  }
#pragma unroll
  for (int i = 0; i < 8; ++i) {
    DA[i] = dist2_rn(PXA[i], PYA[i], PZA[i], p0A.x, p0A.y, p0A.z);
    DB[i] = dist2_rn(PXB[i], PYB[i], PZB[i], p0B.x, p0B.y, p0B.z);
  }
  float qxA = p0A.x, qyA = p0A.y, qzA = p0A.z;
  float qxB = p0B.x, qyB = p0B.y, qzB = p0B.z;

#pragma unroll 1
  for (int s = 1; s < 1024; ++s) {
    if ((s & 63) == 0 && tid < 64) {
      int ia = f.p[0].sIdx[tid];
      float4 pa = f.p[0].sq[ia];
      A.gfP4[(b0 << 10) + (s - 64) + tid] =
          make_float4(kxy * pa.x, kxy * pa.y, kxy * pa.z, pa.w * se);
      int ib = f.p[1].sIdx[tid];
      float4 pb = f.p[1].sq[ib];
      A.gfP4[((b0 + 1) << 10) + (s - 64) + tid] =
          make_float4(kxy * pb.x, kxy * pb.y, kxy * pb.z, pb.w * se);
    }
    int par = s & 1;
    unsigned tagw = (unsigned)(s & 1023);
    // phase 1: batch A leaf + reduce + publish
    unsigned wvA; int wiA;
    leaf_reduce(PXA, PYA, PZA, DA, qxA, qyA, qzA, tid, wvA, wiA);
    if (lane == 0) {
      unsigned long long mine = ((unsigned long long)wvA << 32) |
                                ((unsigned long long)tagw << 16) |
                                (unsigned long long)(unsigned)wiA;
      __hip_atomic_store(&f.p[0].xch[w][par], mine, __ATOMIC_RELAXED,
                         __HIP_MEMORY_SCOPE_WORKGROUP);
    }
    // phase 2: batch B leaf + reduce + publish (hides A's visibility)
    unsigned wvB; int wiB;
    leaf_reduce(PXB, PYB, PZB, DB, qxB, qyB, qzB, tid, wvB, wiB);
    if (lane == 0) {
      unsigned long long mine = ((unsigned long long)wvB << 32) |
                                ((unsigned long long)tagw << 16) |
                                (unsigned long long)(unsigned)wiB;
      __hip_atomic_store(&f.p[1].xch[w][par], mine, __ATOMIC_RELAXED,
                         __HIP_MEMORY_SCOPE_WORKGROUP);
    }
    // phase 3: poll+select A; sq read overlaps phase 4's poll
    int biA = poll_sel(f.p[0].xch, w, par, tagw, wvA, wiA);
    float4 qA = f.p[0].sq[biA];
    // phase 4: poll+select B
    int biB = poll_sel(f.p[1].xch, w, par, tagw, wvB, wiB);
    float4 qB = f.p[1].sq[biB];
    qxA = qA.x; qyA = qA.y; qzA = qA.z;
    qxB = qB.x; qyB = qB.y; qzB = qB.z;
    if (tid == 0) {
      f.p[0].sIdx[s & 63] = biA;
      f.p[1].sIdx[s & 63] = biB;
    }
  }
  if (tid < 64) {
    int ia = f.p[0].sIdx[tid];
    float4 pa = f.p[0].sq[ia];
    A.gfP4[(b0 << 10) + 960 + tid] =
        make_float4(kxy * pa.x, kxy * pa.y, kxy * pa.z, pa.w * se);
    int ib = f.p[1].sIdx[tid];
    float4 pb = f.p[1].sq[ib];
    A.gfP4[((b0 + 1) << 10) + 960 + tid] =
        make_float4(kxy * pb.x, kxy * pb.y, kxy * pb.z, pb.w * se);
  }
  bar_signal(A.sync + SYF(b0), 1u);
  bar_signal(A.sync + SYF(b0 + 1), 1u);
}

// ------------------------ emd1: fenceless dataflow --------------------------
// 16 blocks per batch (chamfer blocks g<64); block owns 64 output columns.
// Single-barrier rounds (parity part[] buffer, per-wave JIT quarter refresh),
// tagged agent-atomic dataflow, distributed assign1 fold (r8 proven).
__device__ void emd1_role(int eb, int chunk, const UniArgs& A, Emd1S& m) {
  int tid = threadIdx.x;
  warm_wait1(A.sync + SYF(eb), 1u);
  for (int t = tid; t < 1024; t += 256) {
    float4 p = A.o1P4[eb * 1024 + t];
    m.rowsO[t] = make_float4(p.x, p.y, p.z, -p.w);
    m.rowsG[t] = A.gfP4[eb * 1024 + t];  // .w overwritten before first use
  }
  int lane = tid & 63, rl = tid >> 6;
  int col = chunk * 64 + lane;
  float4 cG = A.gfP4[eb * 1024 + col];
  float4 cO = A.o1P4[eb * 1024 + col];
  unsigned long long* gv = A.vecT + (eb << 10);          // g side (odd rounds)
  unsigned long long* fv = A.vecT + 4096 + (eb << 10);   // f side (even rounds)
  __syncthreads();  // staging visible to all waves

  for (int s = 1; s <= 21; ++s) {
    int odd = s & 1, par = s & 1;
    if (s >= 2) {
      // per-wave JIT refresh: wave rl owns rows [rl*256, rl*256+256)
      const unsigned long long* v = odd ? fv : gv;
      float4* rows = odd ? m.rowsO : m.rowsG;
      unsigned want = (unsigned)(s - 1);
      int rbase = rl * 256 + lane;
      unsigned long long p0, p1, p2, p3;
      for (;;) {
        p0 = __hip_atomic_load(v + rbase, __ATOMIC_RELAXED, __HIP_MEMORY_SCOPE_AGENT);
        p1 = __hip_atomic_load(v + rbase + 64, __ATOMIC_RELAXED, __HIP_MEMORY_SCOPE_AGENT);
        p2 = __hip_atomic_load(v + rbase + 128, __ATOMIC_RELAXED, __HIP_MEMORY_SCOPE_AGENT);
        p3 = __hip_atomic_load(v + rbase + 192, __ATOMIC_RELAXED, __HIP_MEMORY_SCOPE_AGENT);
        if ((unsigned)(p0 >> 32) >= want && (unsigned)(p1 >> 32) >= want &&
            (unsigned)(p2 >> 32) >= want && (unsigned)(p3 >> 32) >= want)
          break;
        __builtin_amdgcn_s_sleep(1);
      }
      rows[rbase].w = __uint_as_float((unsigned)p0);
      rows[rbase + 64].w = __uint_as_float((unsigned)p1);
      rows[rbase + 128].w = __uint_as_float((unsigned)p2);
      rows[rbase + 192].w = __uint_as_float((unsigned)p3);
    }
    // no barrier: wave rl reads only its own quarter (DS in-order per wave)
    const float4* rows = odd ? m.rowsO : m.rowsG;
    float cx = odd ? cG.x : cO.x;
    float cy = odd ? cG.y : cO.y;
    float cz = odd ? cG.z : cO.z;
#pragma unroll 1
    for (int k = 0; k < 4; ++k) {
      int ch = rl * 4 + k;
      float M = NEGBIG, S = 0.0f;
      int r0 = ch * 64;
#pragma unroll 1
      for (int r = 0; r < 64; r += 8) {
        float4 qq[8];
#pragma unroll
        for (int u = 0; u < 8; ++u) qq[u] = rows[r0 + r + u];
        float t8[8];
#pragma unroll
        for (int u = 0; u < 8; ++u)
          t8[u] = fmaf(cx, qq[u].x, fmaf(cy, qq[u].y, fmaf(cz, qq[u].z, qq[u].w)));
        float cm = fmaxf(fmaxf(fmaxf(t8[0], t8[1]), fmaxf(t8[2], t8[3])),
                         fmaxf(fmaxf(t8[4], t8[5]), fmaxf(t8[6], t8[7])));
        float nM = fmaxf(M, cm);
        float s8 = ((fexp2(t8[0] - nM) + fexp2(t8[1] - nM)) +
                    (fexp2(t8[2] - nM) + fexp2(t8[3] - nM))) +
                   ((fexp2(t8[4] - nM) + fexp2(t8[5] - nM)) +
                    (fexp2(t8[6] - nM) + fexp2(t8[7] - nM)));
        S = fmaf(S, fexp2(M - nM), s8);
        M = nM;
      }
      m.part[par][ch][lane] = make_float2(M, S);
    }
    __syncthreads();  // all part[par] writes done before finalize
    if (tid < 64) {
      float2 pp[16];
#pragma unroll
      for (int c = 0; c < 16; ++c) pp[c] = m.part[par][c][tid];
      float mm = pp[0].x;
#pragma unroll
      for (int c = 1; c < 16; ++c) mm = fmaxf(mm, pp[c].x);
      float ss = 0.0f;
#pragma unroll
      for (int c = 0; c < 16; ++c) ss += pp[c].y * fexp2(pp[c].x - mm);
      float wq = 10.0f - (mm + __log2f(ss));
      unsigned long long pk = ((unsigned long long)(unsigned)s << 32) |
                              (unsigned long long)__float_as_uint(wq);
      __hip_atomic_store((odd ? gv : fv) + col, pk, __ATOMIC_RELAXED,
                         __HIP_MEMORY_SCOPE_AGENT);
    }
    // no second barrier: next round writes part[par^1]; rows refresh is
    // per-wave-local; part[par] reuse is fenced by the NEXT round's barrier.
  }
  __syncthreads();

  // ---- distributed assign1 + combine1: this block owns 64 rows ----
  {
    float w0, w1, w2, w3;
    poll4(gv, tid, 21u, &w0, &w1, &w2, &w3);
    float4 qp0 = A.gfP4[eb * 1024 + tid];
    float4 qp1 = A.gfP4[eb * 1024 + tid + 256];
    float4 qp2 = A.gfP4[eb * 1024 + tid + 512];
    float4 qp3 = A.gfP4[eb * 1024 + tid + 768];
    m.rowsG[tid] = make_float4(qp0.x, qp0.y, qp0.z, w0);
    m.g2[tid] = w0 + qp0.w;
    m.rowsG[tid + 256] = make_float4(qp1.x, qp1.y, qp1.z, w1);
    m.g2[tid + 256] = w1 + qp1.w;
    m.rowsG[tid + 512] = make_float4(qp2.x, qp2.y, qp2.z, w2);
    m.g2[tid + 512] = w2 + qp2.w;
    m.rowsG[tid + 768] = make_float4(qp3.x, qp3.y, qp3.z, w3);
    m.g2[tid + 768] = w3 + qp3.w;
  }
  __syncthreads();
  float eps = *A.epsP;
  float inv_se = eps * LN2;
  int rw = tid & 63, qc = tid >> 6;
  int gi = eb * 1024 + chunk * 64 + rw;
  float4 rp = A.o1P4[gi];
  float rx = rp.x, ry = rp.y, rz = rp.z, xw = rp.w;
  float bW = NEGBIG;
  int bj = 0;
  int t0 = qc * 256;
  for (int t = t0; t < t0 + 256; ++t) {
    float4 q = m.rowsG[t];
    float W = fmaf(rz, q.z, fmaf(ry, q.y, fmaf(rx, q.x, q.w - xw)));
    W = fminf(W, m.g2[t]);
    if (W > bW) { bW = W; bj = t; }
  }
  m.part[0][qc][rw] = make_float2(bW, __int_as_float(bj));
  __syncthreads();
  if (tid < 64) {
    // combine quarters ascending (strict >) == first-max over full scan
    float2 p0 = m.part[0][0][tid];
    float vb = p0.x;
    int vj = __float_as_int(p0.y);
#pragma unroll
    for (int c = 1; c < 4; ++c) {
      float2 p = m.part[0][c][tid];
      if (p.x > vb) { vb = p.x; vj = __float_as_int(p.y); }
    }
    float4 qp = A.gfP4[eb * 1024 + vj];
    float dotp = rp.x * qp.x + rp.y * qp.y + rp.z * qp.z;
    float dd = fmaxf(0.0f, (rp.w + qp.w - dotp) * inv_se);
    float v = sqrtf(dd);
#pragma unroll
    for (int mk = 32; mk; mk >>= 1) v += __shfl_xor(v, mk, 64);
    if (tid == 0) atomicAdd(A.out + 61440 + eb, v * (1.0f / 1024.0f));
  }
  if (chunk == 0) bar_signal(A.sync + SYD(eb), 1u);
}

// ------------------------------ mega-kernel ---------------------------------
// grid 220: 0..1 dual-batch fps | 2..3 spare (exit) | 4..131 emd2 (e<64 then
// warm-spin, e>=64 exit) | 132..219 chamfer (g<64 -> emd1; g>=64 exit).
__global__ __launch_bounds__(256, 1) void uni_kernel(UniArgs A) {
  __shared__ SmemAll sm;
  int bid = blockIdx.x;
  if (bid < 2) {
    fps_role2(A, bid * 2, sm.f);
    return;
  }
  if (bid < 4) return;  // spare CUs
  int e = bid - 4;
  int W = 4 * A.BPB;
  if (e < W) {
    int b = e / A.BPB, rest = e % A.BPB;
    int cb = rest / A.NC2, ch = rest % A.NC2;
    unsigned* slots = A.sync + SY2(b);
    for (int s = 1; s <= 21; ++s) {
      const float4 *rowP, *colP;
      const float2* vp;
      float2* dst;
      if (s & 1) { rowP = A.o2P4; colP = A.gtP4; vp = (s == 1) ? nullptr : A.fpart2; dst = A.gpart2; }
      else       { rowP = A.gtP4; colP = A.o2P4; vp = A.gpart2; dst = A.fpart2; }
      if (A.NC2 == 16) pass2_job<16>(b, cb, ch, rowP, colP, vp, dst, sm.w.ldsRow);
      else             pass2_job<8>(b, cb, ch, rowP, colP, vp, dst, sm.w.ldsRow);
      bar_signal(slots + rest * 16, (unsigned)s);
      bar_waitall<16>(slots, A.BPB, (unsigned)s);
    }
    for (int j = rest; j < 32; j += A.BPB) {
      int cc = j >> 3, rb = j & 7;
      if (A.NC2 == 16) assign2_job<16>(b, cc, rb, A, sm.w);
      else             assign2_job<8>(b, cc, rb, A, sm.w);
    }
    bar_signal(slots + rest * 16, 22u);
    bar_waitall<4>(slots, A.BPB, 22u);
    if (rest < 16) combine2_job(b, rest, A, sm.w);
    // 64 spinners keep clocks warm through the fps/emd1 tail (r6 duty)
    if (e < 64) warm_spin(A);
    return;
  }
  int g = e - W;  // 0..87 chamfer
  chamfer_worker(g, A, sm.w);
  if (g < 64) {
    emd1_role(g >> 4, g & 15, A, sm.e);
  }
  // g>=64: exit
}

// ------------------------------ host launch ---------------------------------
extern "C" void kernel_launch(void* const* d_in, const int* in_sizes, int n_in,
                              void* d_out, int out_size, void* d_ws, size_t ws_size,
                              hipStream_t stream) {
  (void)in_sizes; (void)n_in; (void)out_size;
  const float* o1 = (const float*)d_in[0];
  const float* o2 = (const float*)d_in[1];
  const float* gt = (const float*)d_in[2];
  const float* epsP = (const float*)d_in[3];
  float* out = (float*)d_out;
  float* ws = (float*)d_ws;

  int NC2 = 16;
  {
    size_t need16 = (size_t)(4096 + 16384 + 16384 + 65536 + 65536 + 16384 +
                             2 * (16 * 32768)) * 4;
    if (ws_size < need16) NC2 = 8;
  }
  size_t off = 0;
  unsigned* syncp = (unsigned*)(ws + off); off += 4096;
  unsigned long long* vecT = (unsigned long long*)(ws + off); off += 16384;  // 8192 u64
  float4* o1P4 = (float4*)(ws + off); off += 16384;
  float4* o2P4 = (float4*)(ws + off); off += 65536;
  float4* gtP4 = (float4*)(ws + off); off += 65536;
  float4* gfP4 = (float4*)(ws + off); off += 16384;
  float2* gpart2 = (float2*)(ws + off); off += (size_t)NC2 * 32768;
  float2* fpart2 = (float2*)(ws + off); off += (size_t)NC2 * 32768;
  float2* apart2 = fpart2;  // overlay: fpart2 dead after pass 21

  (void)hipMemcpyAsync(out, o1, 12288 * sizeof(float), hipMemcpyDeviceToDevice, stream);
  (void)hipMemcpyAsync(out + 12288, o2, 49152 * sizeof(float), hipMemcpyDeviceToDevice, stream);
  (void)hipMemsetAsync(out + 61440, 0, 24 * sizeof(float), stream);
  // sync (16 KB) + vecT (64 KB) are adjacent: one memset clears both
  (void)hipMemsetAsync(syncp, 0, (4096 + 16384) * sizeof(float), stream);

  prep_kernel<<<144, 256, 0, stream>>>(o1, o2, gt, epsP, o1P4, o2P4, gtP4);

  UniArgs A;
  A.gt = gt; A.epsP = epsP;
  A.o1P4 = o1P4; A.o2P4 = o2P4; A.gtP4 = gtP4; A.gfP4 = gfP4;
  A.gpart2 = gpart2; A.fpart2 = fpart2; A.apart2 = apart2;
  A.vecT = vecT;
  A.sync = syncp; A.out = out;
  A.NC2 = NC2; A.BPB = 2 * NC2;
  int grid = 4 + 4 * A.BPB + 88;  // 220 at NC2=16
  uni_kernel<<<grid, 256, 0, stream>>>(A);
}

// Round 12
// 1084.748 us; speedup vs baseline: 1.8765x; 1.8765x over previous
//
#include <hip/hip_runtime.h>
#include <math.h>

// ---------------------------------------------------------------------------
// FullModelPCN: FPS + Sinkhorn-EMD (x2) + Chamfer (x2) + passthrough
// B=4; N1=1024 (coarse), N2=4096 (fine/gt).
//
// FINAL (round-22 structure, best measured: 1086 us):
//   Launch 1: prep
//   Launch 2: uni_kernel (grid 220, 1 block/CU):
//     blocks 0..3     : fps 4-wave barrier-free; packed-f32 leaf (compiler-
//                       formed pk ops, bit-exact, contract-off); tree-SCOMB;
//                       my-candidate prefetch + winner==me shortcut; sIdx
//                       ring (flush gathers + transforms).
//     blocks 4..131   : emd2 (128, NC2=16); e<64 warm-spin (r6 duty) until
//                       emd1-done, e>=64 exit.
//     blocks 132..219 : chamfer; g<64 -> emd1 workers (single-barrier rounds,
//                       tagged agent-atomic dataflow, distributed assign1
//                       fold); g>=64 exit.
//
// Session ledger: fps step ~900ns is the surviving floor after 10 structural
// variants (r4/r11 register-spill attempts to widen per-lane state both
// failed: compiler caps VGPR at ~132 for this multi-role kernel and spills).
// emd1 round ~6.7us sits on LLC store->poll visibility (mechanism-
// independent: launches 13.8us, fenced-L2 9us, LLC atomics ~5-6us hidden).
// DVFS: moderate warm-spin -80us (r6); denser/more spinners regress (r7).
// ---------------------------------------------------------------------------

#define LOG2E 1.4426950408889634f
#define LN2   0.6931471805599453f
#define NEGBIG -3.0e38f

// sync region (uints, 4096, memset 0 per call):
//   emd2 slots:  b*512 + j*16           -> [0, 2048)
//   fps-done:    2048 + b*16            -> [2048, 2112)
//   emd1-done:   2112 + b*16            -> [2112, 2176)
#define SY2(b) ((b) * 512)
#define SYF(b) (2048 + (b) * 16)
#define SYD(b) (2112 + (b) * 16)

typedef float f32x2 __attribute__((ext_vector_type(2)));

#if __has_builtin(__builtin_amdgcn_exp2f)
__device__ __forceinline__ float fexp2(float x) { return __builtin_amdgcn_exp2f(x); }
#else
__device__ __forceinline__ float fexp2(float x) { return exp2f(x); }
#endif

__device__ __forceinline__ float dist_rn(float x, float y, float z,
                                         float qx, float qy, float qz) {
  float dx = __fsub_rn(x, qx), dy = __fsub_rn(y, qy), dz = __fsub_rn(z, qz);
  return __fadd_rn(__fadd_rn(__fmul_rn(dx, dx), __fmul_rn(dy, dy)),
                   __fmul_rn(dz, dz));
}

// packed pair distance: per-element IEEE RN sub/mul/add in the exact
// ((xx+yy)+zz) order with contraction OFF -> bit-identical to dist_rn.
__device__ __forceinline__ f32x2 dist2_rn(f32x2 x, f32x2 y, f32x2 z,
                                          float qx, float qy, float qz) {
#pragma clang fp contract(off)
  f32x2 dx = x - qx;
  f32x2 dy = y - qy;
  f32x2 dz = z - qz;
  f32x2 xx = dx * dx;
  f32x2 yy = dy * dy;
  f32x2 zz = dz * dz;
  return (xx + yy) + zz;
}

// ------------------------------ shared memory -------------------------------
struct FpsS {
  float4 sq[4096];
  unsigned long long xch[4][2];  // [wave][step parity] tagged winner
  int sIdx[64];                  // ring of winning indices (steps s&63)
};
struct WorkS {
  float4 ldsRow[256];
  float4 ldsC[1024];
  float ldsG2[1024];
  float red[8];
};
struct Emd1S {
  float4 rowsO[1024];     // o1 points; .w = f-weight (odd-round rows)
  float4 rowsG[1024];     // gt_fps points; .w = g-weight (even-round rows)
  float2 part[2][16][64]; // [round parity][chunk][col-lane] partials
  float g2[1024];         // assign1 fold: w + |q|^2
  float red[8];
};
union SmemAll {
  FpsS f;
  WorkS w;
  Emd1S e;
  float pad_force_one_block_per_cu[21504];  // 86 KB: 1 block/CU guaranteed
};

// ------------------------------ args ----------------------------------------
struct UniArgs {
  const float* gt;
  const float* epsP;
  const float4 *o1P4, *o2P4, *gtP4;
  float4* gfP4;
  float2 *gpart2, *fpart2, *apart2;
  unsigned long long* vecT;  // [0,4096): g tagged; [4096,8192): f tagged
  unsigned* sync;
  float* out;
  int NC2, BPB;
};

// ------------------- distributed-arrival relaxed barriers -------------------
__device__ __forceinline__ void bar_signal(unsigned* slot, unsigned val) {
  __syncthreads();
  if (threadIdx.x == 0)
    __hip_atomic_store(slot, val, __ATOMIC_RELEASE, __HIP_MEMORY_SCOPE_AGENT);
}
template <int SLP>
__device__ __forceinline__ void bar_waitall(const unsigned* base, int n,
                                            unsigned target) {
  if (threadIdx.x < 64) {
    int l = threadIdx.x;
    for (;;) {
      unsigned v = (l < n)
                       ? __hip_atomic_load(base + l * 16, __ATOMIC_RELAXED,
                                           __HIP_MEMORY_SCOPE_AGENT)
                       : target;
      if (__all((int)(v >= target))) break;
      __builtin_amdgcn_s_sleep(SLP);
    }
    if (l == 0)
      (void)__hip_atomic_load(base, __ATOMIC_ACQUIRE, __HIP_MEMORY_SCOPE_AGENT);
  }
  __syncthreads();
}

__device__ __forceinline__ float blockRedSum(float v, float* red4) {
#pragma unroll
  for (int m = 32; m; m >>= 1) v += __shfl_xor(v, m, 64);
  int lane = threadIdx.x & 63, wid = threadIdx.x >> 6;
  __syncthreads();
  if (lane == 0) red4[wid] = v;
  __syncthreads();
  float s = 0.0f;
  if (threadIdx.x == 0) {
#pragma unroll
    for (int w = 0; w < 4; ++w) s += red4[w];
  }
  return s;
}

// ---- branchless 4-wide tagged poll (thread-strided slots) ------------------
__device__ __forceinline__ void poll4(const unsigned long long* v, int tid,
                                      unsigned want, float* w0, float* w1,
                                      float* w2, float* w3) {
  unsigned long long p0, p1, p2, p3;
  for (;;) {
    p0 = __hip_atomic_load(v + tid, __ATOMIC_RELAXED, __HIP_MEMORY_SCOPE_AGENT);
    p1 = __hip_atomic_load(v + tid + 256, __ATOMIC_RELAXED, __HIP_MEMORY_SCOPE_AGENT);
    p2 = __hip_atomic_load(v + tid + 512, __ATOMIC_RELAXED, __HIP_MEMORY_SCOPE_AGENT);
    p3 = __hip_atomic_load(v + tid + 768, __ATOMIC_RELAXED, __HIP_MEMORY_SCOPE_AGENT);
    if ((unsigned)(p0 >> 32) >= want && (unsigned)(p1 >> 32) >= want &&
        (unsigned)(p2 >> 32) >= want && (unsigned)(p3 >> 32) >= want)
      break;
    __builtin_amdgcn_s_sleep(1);
  }
  *w0 = __uint_as_float((unsigned)p0);
  *w1 = __uint_as_float((unsigned)p1);
  *w2 = __uint_as_float((unsigned)p2);
  *w3 = __uint_as_float((unsigned)p3);
}

// ---- moderate FMA burst (r6 duty: ~256 FMAs/poll) --------------------------
__device__ __forceinline__ void fma_burst(float* a) {
#pragma unroll
  for (int i = 0; i < 64; ++i) {
    a[0] = fmaf(a[0], 1.0000001f, 1.0e-6f);
    a[1] = fmaf(a[1], 1.0000001f, 1.0e-6f);
    a[2] = fmaf(a[2], 1.0000001f, 1.0e-6f);
    a[3] = fmaf(a[3], 1.0000001f, 1.0e-6f);
  }
}

// ---- warm spin: FMA until all 4 emd1-done flags set ------------------------
__device__ void warm_spin(const UniArgs& A) {
  float a[4] = {(float)(threadIdx.x + 1), 1.5f, 2.5f, 3.5f};
  const unsigned* sy = A.sync;
  for (;;) {
    unsigned d0 = __hip_atomic_load(sy + SYD(0), __ATOMIC_RELAXED, __HIP_MEMORY_SCOPE_AGENT);
    unsigned d1 = __hip_atomic_load(sy + SYD(1), __ATOMIC_RELAXED, __HIP_MEMORY_SCOPE_AGENT);
    unsigned d2 = __hip_atomic_load(sy + SYD(2), __ATOMIC_RELAXED, __HIP_MEMORY_SCOPE_AGENT);
    unsigned d3 = __hip_atomic_load(sy + SYD(3), __ATOMIC_RELAXED, __HIP_MEMORY_SCOPE_AGENT);
    if ((d0 & d1 & d2 & d3) != 0u) break;
    fma_burst(a);
  }
  asm volatile("" ::"v"(a[0]), "v"(a[1]), "v"(a[2]), "v"(a[3]));
}

// ---- warm wait on one flag (FMA-dense), with acquire + block barrier -------
__device__ void warm_wait1(const unsigned* slot, unsigned target) {
  float a[4] = {(float)(threadIdx.x + 1), 1.5f, 2.5f, 3.5f};
  for (;;) {
    unsigned v = __hip_atomic_load(slot, __ATOMIC_RELAXED, __HIP_MEMORY_SCOPE_AGENT);
    if (v >= target) break;
    fma_burst(a);
  }
  asm volatile("" ::"v"(a[0]), "v"(a[1]), "v"(a[2]), "v"(a[3]));
  if (threadIdx.x == 0)
    (void)__hip_atomic_load(slot, __ATOMIC_ACQUIRE, __HIP_MEMORY_SCOPE_AGENT);
  __syncthreads();
}

// --------------------------- prep: build P4 arrays --------------------------
__global__ __launch_bounds__(256) void prep_kernel(
    const float* __restrict__ o1, const float* __restrict__ o2,
    const float* __restrict__ gt, const float* __restrict__ epsP,
    float4* __restrict__ o1P4, float4* __restrict__ o2P4,
    float4* __restrict__ gtP4) {
  int id = blockIdx.x * 256 + threadIdx.x;  // 0..36863
  float eps = *epsP;
  float se = (1.0f / eps) * LOG2E;
  float kxy = sqrtf(se + se);
  const float* src;
  float4* dst;
  if (id < 4096) { src = o1 + 3 * id; dst = o1P4 + id; }
  else if (id < 20480) { int p = id - 4096; src = o2 + 3 * p; dst = o2P4 + p; }
  else { int p = id - 20480; src = gt + 3 * p; dst = gtP4 + p; }
  float x = src[0], y = src[1], z = src[2];
  float xx = x * x + y * y + z * z;
  *dst = make_float4(kxy * x, kxy * y, kxy * z, xx * se);
}

// --------------------------- Sinkhorn LSE helpers ---------------------------
template <int NC>
__device__ __forceinline__ float finalize_w(const float2* __restrict__ part,
                                            int gi, int stride, float nloga2) {
  float2 pp[NC];
#pragma unroll
  for (int c = 0; c < NC; ++c) pp[c] = part[c * stride + gi];
  float m = pp[0].x;
#pragma unroll
  for (int c = 1; c < NC; ++c) m = fmaxf(m, pp[c].x);
  float s = 0.0f;
#pragma unroll
  for (int c = 0; c < NC; ++c) s += pp[c].y * fexp2(pp[c].x - m);
  return nloga2 - (m + __log2f(s));
}

// emd2 pass: block = (b, cb in 0..1, ch in 0..NC-1); 2048 cols (8/thread)
template <int NC>
__device__ void pass2_job(int b, int cb, int ch, const float4* __restrict__ rowP,
                          const float4* __restrict__ colP,
                          const float2* __restrict__ vpart,
                          float2* __restrict__ dst, float4* ldsRow) {
  const int CH = 4096 / NC;
  int tid = threadIdx.x;
  int gj = b * 4096 + cb * 2048 + tid;
  float cx[8], cy[8], cz[8];
#pragma unroll
  for (int c = 0; c < 8; ++c) {
    float4 cp = colP[gj + (c << 8)];
    cx[c] = cp.x; cy[c] = cp.y; cz[c] = cp.z;
  }
  float M[8], S[8];
#pragma unroll
  for (int c = 0; c < 8; ++c) { M[c] = NEGBIG; S[c] = 0.0f; }
  int r0 = ch * CH;
  for (int t0 = 0; t0 < CH; t0 += 256) {
    __syncthreads();
    {
      int gi = b * 4096 + r0 + t0 + tid;
      float4 rp = rowP[gi];
      float w = vpart ? finalize_w<NC>(vpart, gi, 16384, 12.0f) : -rp.w;
      ldsRow[tid] = make_float4(rp.x, rp.y, rp.z, w);
    }
    __syncthreads();
#pragma unroll 1
    for (int r = 0; r < 256; r += 8) {
      float4 q[8];
#pragma unroll
      for (int u = 0; u < 8; ++u) q[u] = ldsRow[r + u];
#pragma unroll
      for (int c = 0; c < 8; ++c) {
        float t[8];
#pragma unroll
        for (int u = 0; u < 8; ++u)
          t[u] = fmaf(cx[c], q[u].x, fmaf(cy[c], q[u].y, fmaf(cz[c], q[u].z, q[u].w)));
        float cm = fmaxf(fmaxf(fmaxf(t[0], t[1]), fmaxf(t[2], t[3])),
                         fmaxf(fmaxf(t[4], t[5]), fmaxf(t[6], t[7])));
        float nM = fmaxf(M[c], cm);
        float s8 = ((fexp2(t[0] - nM) + fexp2(t[1] - nM)) +
                    (fexp2(t[2] - nM) + fexp2(t[3] - nM))) +
                   ((fexp2(t[4] - nM) + fexp2(t[5] - nM)) +
                    (fexp2(t[6] - nM) + fexp2(t[7] - nM)));
        S[c] = fmaf(S[c], fexp2(M[c] - nM), s8);
        M[c] = nM;
      }
    }
  }
#pragma unroll
  for (int c = 0; c < 8; ++c)
    dst[ch * 16384 + gj + (c << 8)] = make_float2(M[c], S[c]);
}

// ------------------------------- chamfer ------------------------------------
__device__ void cham_job(const float4* __restrict__ aP, const float4* __restrict__ bP,
                         int Na, int Nb, float* outP, float* outT,
                         float scaleP, float scaleT, int b, int rb,
                         WorkS& w, const float* epsP) {
  int tid = threadIdx.x;
  int i0 = rb * 512 + tid, i1 = i0 + 256;
  float4 a0 = aP[b * Na + i0], a1 = aP[b * Na + i1];
  float m0 = 3.0e38f, m1 = 3.0e38f;
  for (int t0 = 0; t0 < Nb; t0 += 1024) {
    __syncthreads();
    for (int t = tid; t < 1024; t += 256) w.ldsC[t] = bP[b * Nb + t0 + t];
    __syncthreads();
#pragma unroll 4
    for (int t = 0; t < 1024; ++t) {
      float4 q = w.ldsC[t];
      float c0 = fmaf(-a0.z, q.z, fmaf(-a0.y, q.y, fmaf(-a0.x, q.x, q.w + a0.w)));
      float c1 = fmaf(-a1.z, q.z, fmaf(-a1.y, q.y, fmaf(-a1.x, q.x, q.w + a1.w)));
      m0 = fminf(m0, c0);
      m1 = fminf(m1, c1);
    }
  }
  float eps = *epsP;
  float inv_se = eps * LN2;
  float d0 = fmaxf(0.0f, m0 * inv_se), d1 = fmaxf(0.0f, m1 * inv_se);
  float s1 = blockRedSum(sqrtf(d0) + sqrtf(d1), w.red);
  float s2 = blockRedSum(d0 + d1, w.red);
  if (tid == 0) {
    atomicAdd(outP, s1 * scaleP);
    atomicAdd(outT, s2 * scaleT);
  }
}

__device__ void chamfer_worker(int g, const UniArgs& A, WorkS& w) {
  for (int cj = g; cj < 104; cj += 88) {
    if (cj < 32) {
      cham_job(A.gtP4, A.o2P4, 4096, 4096, A.out + 61452 + (cj >> 3),
               A.out + 61460 + (cj >> 3), 1.0f / 8192.0f, 1.0f / 4096.0f,
               cj >> 3, cj & 7, w, A.epsP);
    } else if (cj < 64) {
      int j = cj - 32;
      cham_job(A.o2P4, A.gtP4, 4096, 4096, A.out + 61452 + (j >> 3),
               A.out + 61460 + (j >> 3), 1.0f / 8192.0f, 1.0f / 4096.0f,
               j >> 3, j & 7, w, A.epsP);
    } else if (cj < 96) {
      int j = cj - 64;
      cham_job(A.gtP4, A.o1P4, 4096, 1024, A.out + 61448 + (j >> 3),
               A.out + 61456 + (j >> 3), 1.0f / 8192.0f, 1.0f / 4096.0f,
               j >> 3, j & 7, w, A.epsP);
    } else {
      int j = cj - 96;
      cham_job(A.o1P4, A.gtP4, 1024, 4096, A.out + 61448 + (j >> 1),
               A.out + 61456 + (j >> 1), 1.0f / 2048.0f, 1.0f / 1024.0f,
               j >> 1, j & 1, w, A.epsP);
    }
  }
}

// ------------------------------- assign2 ------------------------------------
template <int NC>
__device__ void assign2_job(int b, int cc, int rb, const UniArgs& A, WorkS& w) {
  int tid = threadIdx.x;
  __syncthreads();
  for (int t = tid; t < 1024; t += 256) {
    int gjc = b * 4096 + cc * 1024 + t;
    float wv = finalize_w<NC>(A.gpart2, gjc, 16384, 12.0f);
    float4 qp = A.gtP4[gjc];
    w.ldsC[t] = make_float4(qp.x, qp.y, qp.z, wv);
    w.ldsG2[t] = wv + qp.w;
  }
  __syncthreads();
#pragma unroll
  for (int rr = 0; rr < 2; ++rr) {
    int gi = b * 4096 + rb * 512 + (rr << 8) + tid;
    float4 rp = A.o2P4[gi];
    float rx = rp.x, ry = rp.y, rz = rp.z, xw = rp.w;
    float bW = NEGBIG;
    int bj = 0;
    for (int t = 0; t < 1024; ++t) {
      float4 q = w.ldsC[t];
      float W = fmaf(rz, q.z, fmaf(ry, q.y, fmaf(rx, q.x, q.w - xw)));
      W = fminf(W, w.ldsG2[t]);
      if (W > bW) { bW = W; bj = cc * 1024 + t; }
    }
    A.apart2[cc * 16384 + gi] = make_float2(bW, __int_as_float(bj));
  }
}

__device__ void combine2_job(int b, int rb, const UniArgs& A, WorkS& w) {
  int tid = threadIdx.x;
  int gi = b * 4096 + (rb << 8) + tid;
  float bW = NEGBIG;
  int bj = 0;
#pragma unroll
  for (int c = 0; c < 4; ++c) {
    float2 p = A.apart2[c * 16384 + gi];
    if (p.x > bW) { bW = p.x; bj = __float_as_int(p.y); }
  }
  float eps = *A.epsP;
  float inv_se = eps * LN2;
  float4 rp = A.o2P4[gi];
  float4 qp = A.gtP4[b * 4096 + bj];
  float dotp = rp.x * qp.x + rp.y * qp.y + rp.z * qp.z;
  float d = fmaxf(0.0f, (rp.w + qp.w - dotp) * inv_se);
  float s = blockRedSum(sqrtf(d), w.red);
  if (tid == 0) atomicAdd(A.out + 61444 + b, s * (1.0f / 4096.0f));
}

// --------------------------------- FPS --------------------------------------
// 4-wave barrier-free (r8 proven): packed-f32 leaf (compiler-formed pk ops,
// bit-exact), tree-SCOMB, my-candidate prefetch + winner==me shortcut,
// tagged parity LDS slots, sIdx ring (flush gathers + transforms).
__device__ void fps_role(const UniArgs& A, int b, FpsS& f) {
  int tid = threadIdx.x;
  const float* base = A.gt + b * 12288;
  for (int t = tid; t < 4096; t += 256) {
    float x = base[3 * t], y = base[3 * t + 1], z = base[3 * t + 2];
    f.sq[t] = make_float4(x, y, z, x * x + y * y + z * z);
  }
  if (tid < 8) ((unsigned long long*)f.xch)[tid] = 0ull;
  if (tid == 0) f.sIdx[0] = 0;
  __syncthreads();
  float eps = *A.epsP;
  float se = (1.0f / eps) * LOG2E;
  float kxy = sqrtf(se + se);
  float4 p0 = f.sq[0];
  f32x2 PX[8], PY[8], PZ[8];
  float d[16];
#pragma unroll
  for (int k = 0; k < 16; ++k) {
    float4 p = f.sq[tid + (k << 8)];
    PX[k >> 1][k & 1] = p.x;
    PY[k >> 1][k & 1] = p.y;
    PZ[k >> 1][k & 1] = p.z;
    d[k] = dist_rn(p.x, p.y, p.z, p0.x, p0.y, p0.z);
  }
  int lane = tid & 63, w = tid >> 6;
  float qx = p0.x, qy = p0.y, qz = p0.z;
  unsigned long long* xmine = &f.xch[w][0];

#define DPPSTEP(C)                                                             \
  {                                                                            \
    unsigned ov = (unsigned)__builtin_amdgcn_update_dpp(0, (int)bvu, C, 0xf,  \
                                                        0xf, true);           \
    int oi = __builtin_amdgcn_update_dpp(0, bi, C, 0xf, 0xf, true);           \
    bool t = (ov > bvu) || ((ov == bvu) && ((unsigned)oi < (unsigned)bi));    \
    bvu = t ? ov : bvu;                                                        \
    bi = t ? oi : bi;                                                          \
  }
#define XCOMB(G)                                                               \
  {                                                                            \
    unsigned _v = (unsigned)((G) >> 32);                                       \
    int _i = (int)((unsigned)(G) & 0xFFFu);                                    \
    if (_v > bv2 || (_v == bv2 && _i < bi2)) { bv2 = _v; bi2 = _i; }          \
  }

#pragma unroll 1
  for (int s = 1; s < 1024; ++s) {
    if ((s & 63) == 0 && tid < 64) {
      int idx = f.sIdx[tid];
      float4 p = f.sq[idx];
      A.gfP4[(b << 10) + (s - 64) + tid] =
          make_float4(kxy * p.x, kxy * p.y, kxy * p.z, p.w * se);
    }
    // leaf: packed distance pairs + fused min-update + merge (bit-identical)
    float tv[8]; int ti[8];
#pragma unroll
    for (int i = 0; i < 8; ++i) {
      f32x2 nn = dist2_rn(PX[i], PY[i], PZ[i], qx, qy, qz);
      float n0 = fminf(d[2 * i], nn[0]);
      float n1 = fminf(d[2 * i + 1], nn[1]);
      d[2 * i] = n0;
      d[2 * i + 1] = n1;
      bool t = n1 > n0;
      tv[i] = t ? n1 : n0;
      ti[i] = tid + ((t ? (2 * i + 1) : (2 * i)) << 8);
    }
    float uv[4]; int ui[4];
#pragma unroll
    for (int i = 0; i < 4; ++i) {
      bool t = tv[2 * i + 1] > tv[2 * i];
      uv[i] = t ? tv[2 * i + 1] : tv[2 * i];
      ui[i] = t ? ti[2 * i + 1] : ti[2 * i];
    }
    bool tA = uv[1] > uv[0];
    float vA = tA ? uv[1] : uv[0]; int iA = tA ? ui[1] : ui[0];
    bool tB = uv[3] > uv[2];
    float vB = tB ? uv[3] : uv[2]; int iB = tB ? ui[3] : ui[2];
    bool tC = vB > vA;
    float bv = tC ? vB : vA; int bi = tC ? iB : iA;
    unsigned bvu = __float_as_uint(bv);
    DPPSTEP(0xB1)
    DPPSTEP(0x4E)
    DPPSTEP(0x141)
    DPPSTEP(0x140)
    // tree combine of the 4 row winners (lexicographic max: associative)
    unsigned r0v = (unsigned)__builtin_amdgcn_readlane((int)bvu, 0);
    int r0i = __builtin_amdgcn_readlane(bi, 0);
    unsigned r1v = (unsigned)__builtin_amdgcn_readlane((int)bvu, 16);
    int r1i = __builtin_amdgcn_readlane(bi, 16);
    unsigned r2v = (unsigned)__builtin_amdgcn_readlane((int)bvu, 32);
    int r2i = __builtin_amdgcn_readlane(bi, 32);
    unsigned r3v = (unsigned)__builtin_amdgcn_readlane((int)bvu, 48);
    int r3i = __builtin_amdgcn_readlane(bi, 48);
    bool tP = (r1v > r0v) || (r1v == r0v && r1i < r0i);
    unsigned pv = tP ? r1v : r0v; int pi = tP ? r1i : r0i;
    bool tQ = (r3v > r2v) || (r3v == r2v && r3i < r2i);
    unsigned qv = tQ ? r3v : r2v; int qi = tQ ? r3i : r2i;
    bool tR = (qv > pv) || (qv == pv && qi < pi);
    unsigned wv = tR ? qv : pv; int wi = tR ? qi : pi;
    // publish my wave winner, then prefetch its coords (hidden under poll)
    int par = s & 1;
    unsigned tagw = (unsigned)(s & 1023);
    unsigned long long mine = ((unsigned long long)wv << 32) |
                              ((unsigned long long)tagw << 16) |
                              (unsigned long long)(unsigned)wi;
    if (lane == 0)
      __hip_atomic_store(xmine + par, mine, __ATOMIC_RELAXED,
                         __HIP_MEMORY_SCOPE_WORKGROUP);
    float4 mq = f.sq[wi];
    unsigned long long g1, g2, g3;
    for (;;) {
      g1 = __hip_atomic_load(&f.xch[(w + 1) & 3][par], __ATOMIC_RELAXED,
                             __HIP_MEMORY_SCOPE_WORKGROUP);
      g2 = __hip_atomic_load(&f.xch[(w + 2) & 3][par], __ATOMIC_RELAXED,
                             __HIP_MEMORY_SCOPE_WORKGROUP);
      g3 = __hip_atomic_load(&f.xch[(w + 3) & 3][par], __ATOMIC_RELAXED,
                             __HIP_MEMORY_SCOPE_WORKGROUP);
      if ((((unsigned)(g1 >> 16) & 1023u) == tagw) &
          (((unsigned)(g2 >> 16) & 1023u) == tagw) &
          (((unsigned)(g3 >> 16) & 1023u) == tagw))
        break;
    }
    unsigned bv2 = wv; int bi2 = wi;
    XCOMB(g1) XCOMB(g2) XCOMB(g3)
    float4 q;
    if (bv2 == wv && bi2 == wi) q = mq;   // my wave won (uniform branch)
    else q = f.sq[bi2];
    qx = q.x; qy = q.y; qz = q.z;
    if (tid == 0) f.sIdx[s & 63] = bi2;
  }
#undef DPPSTEP
#undef XCOMB
  if (tid < 64) {
    int idx = f.sIdx[tid];
    float4 p = f.sq[idx];
    A.gfP4[(b << 10) + 960 + tid] =
        make_float4(kxy * p.x, kxy * p.y, kxy * p.z, p.w * se);
  }
  bar_signal(A.sync + SYF(b), 1u);
}

// ------------------------ emd1: fenceless dataflow --------------------------
// 16 blocks per batch (chamfer blocks g<64); block owns 64 output columns.
// Single-barrier rounds (parity part[] buffer, per-wave JIT quarter refresh),
// tagged agent-atomic dataflow, distributed assign1 fold (r8 proven).
__device__ void emd1_role(int eb, int chunk, const UniArgs& A, Emd1S& m) {
  int tid = threadIdx.x;
  warm_wait1(A.sync + SYF(eb), 1u);
  for (int t = tid; t < 1024; t += 256) {
    float4 p = A.o1P4[eb * 1024 + t];
    m.rowsO[t] = make_float4(p.x, p.y, p.z, -p.w);
    m.rowsG[t] = A.gfP4[eb * 1024 + t];  // .w overwritten before first use
  }
  int lane = tid & 63, rl = tid >> 6;
  int col = chunk * 64 + lane;
  float4 cG = A.gfP4[eb * 1024 + col];
  float4 cO = A.o1P4[eb * 1024 + col];
  unsigned long long* gv = A.vecT + (eb << 10);          // g side (odd rounds)
  unsigned long long* fv = A.vecT + 4096 + (eb << 10);   // f side (even rounds)
  __syncthreads();  // staging visible to all waves

  for (int s = 1; s <= 21; ++s) {
    int odd = s & 1, par = s & 1;
    if (s >= 2) {
      // per-wave JIT refresh: wave rl owns rows [rl*256, rl*256+256)
      const unsigned long long* v = odd ? fv : gv;
      float4* rows = odd ? m.rowsO : m.rowsG;
      unsigned want = (unsigned)(s - 1);
      int rbase = rl * 256 + lane;
      unsigned long long p0, p1, p2, p3;
      for (;;) {
        p0 = __hip_atomic_load(v + rbase, __ATOMIC_RELAXED, __HIP_MEMORY_SCOPE_AGENT);
        p1 = __hip_atomic_load(v + rbase + 64, __ATOMIC_RELAXED, __HIP_MEMORY_SCOPE_AGENT);
        p2 = __hip_atomic_load(v + rbase + 128, __ATOMIC_RELAXED, __HIP_MEMORY_SCOPE_AGENT);
        p3 = __hip_atomic_load(v + rbase + 192, __ATOMIC_RELAXED, __HIP_MEMORY_SCOPE_AGENT);
        if ((unsigned)(p0 >> 32) >= want && (unsigned)(p1 >> 32) >= want &&
            (unsigned)(p2 >> 32) >= want && (unsigned)(p3 >> 32) >= want)
          break;
        __builtin_amdgcn_s_sleep(1);
      }
      rows[rbase].w = __uint_as_float((unsigned)p0);
      rows[rbase + 64].w = __uint_as_float((unsigned)p1);
      rows[rbase + 128].w = __uint_as_float((unsigned)p2);
      rows[rbase + 192].w = __uint_as_float((unsigned)p3);
    }
    // no barrier: wave rl reads only its own quarter (DS in-order per wave)
    const float4* rows = odd ? m.rowsO : m.rowsG;
    float cx = odd ? cG.x : cO.x;
    float cy = odd ? cG.y : cO.y;
    float cz = odd ? cG.z : cO.z;
#pragma unroll 1
    for (int k = 0; k < 4; ++k) {
      int ch = rl * 4 + k;
      float M = NEGBIG, S = 0.0f;
      int r0 = ch * 64;
#pragma unroll 1
      for (int r = 0; r < 64; r += 8) {
        float4 qq[8];
#pragma unroll
        for (int u = 0; u < 8; ++u) qq[u] = rows[r0 + r + u];
        float t8[8];
#pragma unroll
        for (int u = 0; u < 8; ++u)
          t8[u] = fmaf(cx, qq[u].x, fmaf(cy, qq[u].y, fmaf(cz, qq[u].z, qq[u].w)));
        float cm = fmaxf(fmaxf(fmaxf(t8[0], t8[1]), fmaxf(t8[2], t8[3])),
                         fmaxf(fmaxf(t8[4], t8[5]), fmaxf(t8[6], t8[7])));
        float nM = fmaxf(M, cm);
        float s8 = ((fexp2(t8[0] - nM) + fexp2(t8[1] - nM)) +
                    (fexp2(t8[2] - nM) + fexp2(t8[3] - nM))) +
                   ((fexp2(t8[4] - nM) + fexp2(t8[5] - nM)) +
                    (fexp2(t8[6] - nM) + fexp2(t8[7] - nM)));
        S = fmaf(S, fexp2(M - nM), s8);
        M = nM;
      }
      m.part[par][ch][lane] = make_float2(M, S);
    }
    __syncthreads();  // all part[par] writes done before finalize
    if (tid < 64) {
      float2 pp[16];
#pragma unroll
      for (int c = 0; c < 16; ++c) pp[c] = m.part[par][c][tid];
      float mm = pp[0].x;
#pragma unroll
      for (int c = 1; c < 16; ++c) mm = fmaxf(mm, pp[c].x);
      float ss = 0.0f;
#pragma unroll
      for (int c = 0; c < 16; ++c) ss += pp[c].y * fexp2(pp[c].x - mm);
      float wq = 10.0f - (mm + __log2f(ss));
      unsigned long long pk = ((unsigned long long)(unsigned)s << 32) |
                              (unsigned long long)__float_as_uint(wq);
      __hip_atomic_store((odd ? gv : fv) + col, pk, __ATOMIC_RELAXED,
                         __HIP_MEMORY_SCOPE_AGENT);
    }
    // no second barrier: next round writes part[par^1]; rows refresh is
    // per-wave-local; part[par] reuse is fenced by the NEXT round's barrier.
  }
  __syncthreads();

  // ---- distributed assign1 + combine1: this block owns 64 rows ----
  {
    float w0, w1, w2, w3;
    poll4(gv, tid, 21u, &w0, &w1, &w2, &w3);
    float4 qp0 = A.gfP4[eb * 1024 + tid];
    float4 qp1 = A.gfP4[eb * 1024 + tid + 256];
    float4 qp2 = A.gfP4[eb * 1024 + tid + 512];
    float4 qp3 = A.gfP4[eb * 1024 + tid + 768];
    m.rowsG[tid] = make_float4(qp0.x, qp0.y, qp0.z, w0);
    m.g2[tid] = w0 + qp0.w;
    m.rowsG[tid + 256] = make_float4(qp1.x, qp1.y, qp1.z, w1);
    m.g2[tid + 256] = w1 + qp1.w;
    m.rowsG[tid + 512] = make_float4(qp2.x, qp2.y, qp2.z, w2);
    m.g2[tid + 512] = w2 + qp2.w;
    m.rowsG[tid + 768] = make_float4(qp3.x, qp3.y, qp3.z, w3);
    m.g2[tid + 768] = w3 + qp3.w;
  }
  __syncthreads();
  float eps = *A.epsP;
  float inv_se = eps * LN2;
  int rw = tid & 63, qc = tid >> 6;
  int gi = eb * 1024 + chunk * 64 + rw;
  float4 rp = A.o1P4[gi];
  float rx = rp.x, ry = rp.y, rz = rp.z, xw = rp.w;
  float bW = NEGBIG;
  int bj = 0;
  int t0 = qc * 256;
  for (int t = t0; t < t0 + 256; ++t) {
    float4 q = m.rowsG[t];
    float W = fmaf(rz, q.z, fmaf(ry, q.y, fmaf(rx, q.x, q.w - xw)));
    W = fminf(W, m.g2[t]);
    if (W > bW) { bW = W; bj = t; }
  }
  m.part[0][qc][rw] = make_float2(bW, __int_as_float(bj));
  __syncthreads();
  if (tid < 64) {
    // combine quarters ascending (strict >) == first-max over full scan
    float2 p0 = m.part[0][0][tid];
    float vb = p0.x;
    int vj = __float_as_int(p0.y);
#pragma unroll
    for (int c = 1; c < 4; ++c) {
      float2 p = m.part[0][c][tid];
      if (p.x > vb) { vb = p.x; vj = __float_as_int(p.y); }
    }
    float4 qp = A.gfP4[eb * 1024 + vj];
    float dotp = rp.x * qp.x + rp.y * qp.y + rp.z * qp.z;
    float dd = fmaxf(0.0f, (rp.w + qp.w - dotp) * inv_se);
    float v = sqrtf(dd);
#pragma unroll
    for (int mk = 32; mk; mk >>= 1) v += __shfl_xor(v, mk, 64);
    if (tid == 0) atomicAdd(A.out + 61440 + eb, v * (1.0f / 1024.0f));
  }
  if (chunk == 0) bar_signal(A.sync + SYD(eb), 1u);
}

// ------------------------------ mega-kernel ---------------------------------
// grid 220: 0..3 fps | 4..131 emd2 (e<64 then warm-spin, e>=64 exit) |
// 132..219 chamfer (g<64 -> emd1 workers; g>=64 exit).
__global__ __launch_bounds__(256, 1) void uni_kernel(UniArgs A) {
  __shared__ SmemAll sm;
  int bid = blockIdx.x;
  if (bid < 4) {
    fps_role(A, bid, sm.f);
    return;
  }
  int e = bid - 4;
  int W = 4 * A.BPB;
  if (e < W) {
    int b = e / A.BPB, rest = e % A.BPB;
    int cb = rest / A.NC2, ch = rest % A.NC2;
    unsigned* slots = A.sync + SY2(b);
    for (int s = 1; s <= 21; ++s) {
      const float4 *rowP, *colP;
      const float2* vp;
      float2* dst;
      if (s & 1) { rowP = A.o2P4; colP = A.gtP4; vp = (s == 1) ? nullptr : A.fpart2; dst = A.gpart2; }
      else       { rowP = A.gtP4; colP = A.o2P4; vp = A.gpart2; dst = A.fpart2; }
      if (A.NC2 == 16) pass2_job<16>(b, cb, ch, rowP, colP, vp, dst, sm.w.ldsRow);
      else             pass2_job<8>(b, cb, ch, rowP, colP, vp, dst, sm.w.ldsRow);
      bar_signal(slots + rest * 16, (unsigned)s);
      bar_waitall<16>(slots, A.BPB, (unsigned)s);
    }
    for (int j = rest; j < 32; j += A.BPB) {
      int cc = j >> 3, rb = j & 7;
      if (A.NC2 == 16) assign2_job<16>(b, cc, rb, A, sm.w);
      else             assign2_job<8>(b, cc, rb, A, sm.w);
    }
    bar_signal(slots + rest * 16, 22u);
    bar_waitall<4>(slots, A.BPB, 22u);
    if (rest < 16) combine2_job(b, rest, A, sm.w);
    // 64 spinners keep clocks warm through the fps/emd1 tail (r6 duty)
    if (e < 64) warm_spin(A);
    return;
  }
  int g = e - W;  // 0..87 chamfer
  chamfer_worker(g, A, sm.w);
  if (g < 64) {
    emd1_role(g >> 4, g & 15, A, sm.e);
  }
  // g>=64: exit
}

// ------------------------------ host launch ---------------------------------
extern "C" void kernel_launch(void* const* d_in, const int* in_sizes, int n_in,
                              void* d_out, int out_size, void* d_ws, size_t ws_size,
                              hipStream_t stream) {
  (void)in_sizes; (void)n_in; (void)out_size;
  const float* o1 = (const float*)d_in[0];
  const float* o2 = (const float*)d_in[1];
  const float* gt = (const float*)d_in[2];
  const float* epsP = (const float*)d_in[3];
  float* out = (float*)d_out;
  float* ws = (float*)d_ws;

  int NC2 = 16;
  {
    size_t need16 = (size_t)(4096 + 16384 + 16384 + 65536 + 65536 + 16384 +
                             2 * (16 * 32768)) * 4;
    if (ws_size < need16) NC2 = 8;
  }
  size_t off = 0;
  unsigned* syncp = (unsigned*)(ws + off); off += 4096;
  unsigned long long* vecT = (unsigned long long*)(ws + off); off += 16384;  // 8192 u64
  float4* o1P4 = (float4*)(ws + off); off += 16384;
  float4* o2P4 = (float4*)(ws + off); off += 65536;
  float4* gtP4 = (float4*)(ws + off); off += 65536;
  float4* gfP4 = (float4*)(ws + off); off += 16384;
  float2* gpart2 = (float2*)(ws + off); off += (size_t)NC2 * 32768;
  float2* fpart2 = (float2*)(ws + off); off += (size_t)NC2 * 32768;
  float2* apart2 = fpart2;  // overlay: fpart2 dead after pass 21

  (void)hipMemcpyAsync(out, o1, 12288 * sizeof(float), hipMemcpyDeviceToDevice, stream);
  (void)hipMemcpyAsync(out + 12288, o2, 49152 * sizeof(float), hipMemcpyDeviceToDevice, stream);
  (void)hipMemsetAsync(out + 61440, 0, 24 * sizeof(float), stream);
  // sync (16 KB) + vecT (64 KB) are adjacent: one memset clears both
  (void)hipMemsetAsync(syncp, 0, (4096 + 16384) * sizeof(float), stream);

  prep_kernel<<<144, 256, 0, stream>>>(o1, o2, gt, epsP, o1P4, o2P4, gtP4);

  UniArgs A;
  A.gt = gt; A.epsP = epsP;
  A.o1P4 = o1P4; A.o2P4 = o2P4; A.gtP4 = gtP4; A.gfP4 = gfP4;
  A.gpart2 = gpart2; A.fpart2 = fpart2; A.apart2 = apart2;
  A.vecT = vecT;
  A.sync = syncp; A.out = out;
  A.NC2 = NC2; A.BPB = 2 * NC2;
  int grid = 4 + 4 * A.BPB + 88;  // 220 at NC2=16
  uni_kernel<<<grid, 256, 0, stream>>>(A);
}